// Round 12
// baseline (91.709 us; speedup 1.0000x reference)
//
#include <hip/hip_runtime.h>
#include <hip/hip_bf16.h>

typedef float f32x16 __attribute__((ext_vector_type(16)));
typedef short short8 __attribute__((ext_vector_type(8)));

#define N_IMG 32
#define C_CH  128
#define HW    9216
#define K_CL  64
#define EPSF  1e-12f

#define BPI   24      // blocks per image
#define PPB   384     // pixels per block
#define NHALF 6       // 6 half-tiles of 64 pixels

// ws layout (floats)
#define WS_VLAD 0
#define WS_ASUM (N_IMG*K_CL*C_CH)              // 262144
#define WS_ZERO (WS_ASUM + N_IMG*K_CL)         // 264192 (zeroed prefix, atomic path)
#define WS_PART WS_ZERO
#define NPART   (N_IMG*BPI)                    // 768
// part stored as bf16 (ushort)
#define WS_ASP  (WS_PART + NPART*K_CL*C_CH/2)  // + 3145728
#define WS_STORE_TOT (WS_ASP + NPART*K_CL)

__device__ __forceinline__ unsigned short bfb(float f) {
    __hip_bfloat16 h = __float2bfloat16(f);   // RNE
    return *reinterpret_cast<unsigned short*>(&h);
}
__device__ __forceinline__ float b2f(unsigned short s) {
    return __uint_as_float(((unsigned)s) << 16);
}

__global__ void k_zero(float* __restrict__ p, int cnt) {
    int i = blockIdx.x * blockDim.x + threadIdx.x;
    if (i < cnt) p[i] = 0.f;
}

__global__ __launch_bounds__(256, 3) void k_fused9(
    const float* __restrict__ x, const float* __restrict__ conv_w,
    float* __restrict__ vlad, float* __restrict__ asum,
    unsigned short* __restrict__ part, float* __restrict__ aspart, int use_part)
{
    // cw: pitch 256B, swz ^((k&7)<<4). s/xs: pitch 128B, swz ^((row&7)<<4)
    __shared__ __align__(16) char cw_lds[64 * 256];     // conv_w bf16 [64k][128c] 16KB
    __shared__ __align__(16) char s_lds [64 * 128];     // soft*scn bf16 [64k][64p] 8KB
    __shared__ __align__(16) char xs_lds[128 * 128];    // raw x bf16 [128c][64p] 16KB
    __shared__ __align__(16) float smpart[2][64];       // softmax-denominator halves
    __shared__ __align__(16) float normt[64];           // per-pixel ||x|| (fp32)

    const int t  = threadIdx.x;
    const int w  = t >> 6;          // wave 0..3
    const int l  = t & 63;
    const int lp = l & 31;
    const int h  = l >> 5;
    const int n    = blockIdx.x / BPI;
    const int pblk = (blockIdx.x % BPI) * PPB;

    // ---- stage conv_w -> bf16, swizzled (pitch 256) ----
    #pragma unroll
    for (int r = 0; r < 16; ++r) {
        int e  = t + 256 * r;          // bf16-pair index 0..4095
        int k  = e >> 6;
        int c2 = (e & 63) << 1;
        unsigned pa = (unsigned)bfb(conv_w[k * C_CH + c2]) |
                      ((unsigned)bfb(conv_w[k * C_CH + c2 + 1]) << 16);
        int addr = (((k << 8) | (c2 << 1)) ^ ((k & 7) << 4));
        *reinterpret_cast<unsigned*>(cw_lds + addr) = pa;
    }

    f32x16 va0, va1;
    #pragma unroll
    for (int r = 0; r < 16; ++r) { va0[r] = 0.f; va1[r] = 0.f; }
    float asum_acc = 0.f;

    const int kh   = w >> 1;         // logits k-half of this wave
    const int p    = (w & 1) * 32 + lp;   // this lane's pixel 0..63 in half-tile
    const int ks   = t >> 2;         // asum: my k row
    const int st4  = t & 3;          // asum: my 16-pixel strip
    const float* xbase = x + (size_t)n * C_CH * HW;

    // transit assignment: 4 px x 8 c-rows per thread
    const int px4 = (t & 15) << 2;   // 0,4,...,60
    const int c0  = t >> 4;          // 0..15 (c = c0 + 16j)
    const int tswz = (c0 & 7) << 4;  // thread-uniform xs swizzle

    // LDS bases
    const int swzL = (lp & 7) << 4;
    const int hx   = h << 4;
    const int bCW  = ((kh * 32 + lp) << 8) | (hx ^ swzL);  // logits A base (^ s<<5)
    const int cB   = 32 * w + lp;                           // VLAD c-column
    const int bXf  = (cB << 7) | (hx ^ swzL);              // VLAD B base (cB&7==lp&7)
    const int bS0  = (lp << 7)        | (hx ^ swzL);       // VLAD A rows lp
    const int bS1  = ((32 + lp) << 7) | (hx ^ swzL);       // VLAD A rows 32+lp
    const int p2   = p << 1;                                // byte offset of pixel col

    // ---- prologue: transit half 0 ----
    {
        const float* xsrc = xbase + pblk + px4;
        float4 v[8];
        #pragma unroll
        for (int j = 0; j < 8; ++j)
            v[j] = *reinterpret_cast<const float4*>(xsrc + (size_t)(c0 + 16 * j) * HW);
        #pragma unroll
        for (int j = 0; j < 8; ++j) {
            int c = c0 + 16 * j;
            uint2 pk;
            pk.x = (unsigned)bfb(v[j].x) | ((unsigned)bfb(v[j].y) << 16);
            pk.y = (unsigned)bfb(v[j].z) | ((unsigned)bfb(v[j].w) << 16);
            *reinterpret_cast<uint2*>(xs_lds + ((c << 7) | ((px4 << 1) ^ tswz))) = pk;
        }
    }
    __syncthreads();   // cw + xs(0) ready

    for (int it = 0; it < NHALF; ++it) {
        // ---- fragment assembly + sumsq from xs_lds (raw bf16) ----
        float ss = 0.f;
        short8 xb[8];
        #pragma unroll
        for (int s8 = 0; s8 < 8; ++s8) {
            #pragma unroll
            for (int i = 0; i < 8; ++i) {
                const int c = 16 * s8 + 8 * h + i;        // c&7 == i
                short v = *reinterpret_cast<const short*>(
                    xs_lds + ((c << 7) | (p2 ^ (i << 4))));
                float f = b2f((unsigned short)v);
                ss += f * f;
                xb[s8][i] = v;
            }
        }
        ss += __shfl_xor(ss, 32);
        const float nrm = fmaxf(sqrtf(ss), EPSF);
        const float scn = 1.f / nrm;

        // ---- issue next half's transit loads (hidden under MFMA/softmax) ----
        float4 v[8];
        if (it + 1 < NHALF) {
            const float* xsrc = xbase + pblk + (it + 1) * 64 + px4;
            #pragma unroll
            for (int j = 0; j < 8; ++j)
                v[j] = *reinterpret_cast<const float4*>(xsrc + (size_t)(c0 + 16 * j) * HW);
        }

        // ---- logits MFMA: this wave = [32k x 32p], K=128 ----
        f32x16 d;
        #pragma unroll
        for (int r = 0; r < 16; ++r) d[r] = 0.f;
        #pragma unroll
        for (int s8 = 0; s8 < 8; ++s8) {
            short8 a = *reinterpret_cast<const short8*>(cw_lds + (bCW ^ (s8 << 5)));
            d = __builtin_amdgcn_mfma_f32_32x32x16_bf16(a, xb[s8], d, 0, 0, 0);
        }

        // ---- e = exp(d*scn) (no max needed: |d*scn| <= ~1.4); partial denom ----
        float e[16];
        float sm = 0.f;
        #pragma unroll
        for (int r = 0; r < 16; ++r) { e[r] = __expf(d[r] * scn); sm += e[r]; }
        sm += __shfl_xor(sm, 32);
        if (h == 0) smpart[kh][p] = sm;
        __syncthreads();   // A: smpart ready (+ prev-iter s_lds readers done)

        const float inv = 1.f / (smpart[0][p] + smpart[1][p]);
        const float esc = inv * scn;
        #pragma unroll
        for (int r = 0; r < 16; ++r) {
            const int kr = (r & 3) + 8 * (r >> 2) + 4 * h;
            const int k  = kh * 32 + kr;                  // k&7 == (r&3)+4h
            *reinterpret_cast<short*>(
                s_lds + ((k << 7) | (p2 ^ (((r & 3) + 4 * h) << 4)))) =
                (short)bfb(e[r] * esc);
        }
        if (h == 0 && kh == 0) normt[p] = nrm;
        __syncthreads();   // B: s_lds + normt ready

        // ---- VLAD MFMA: [64k x 128c], K = 64 pixels; B = raw x from xs_lds ----
        #pragma unroll
        for (int sp = 0; sp < 4; ++sp) {
            short8 bf = *reinterpret_cast<const short8*>(xs_lds + (bXf ^ (sp << 5)));
            short8 s0 = *reinterpret_cast<const short8*>(s_lds  + (bS0 ^ (sp << 5)));
            short8 s1 = *reinterpret_cast<const short8*>(s_lds  + (bS1 ^ (sp << 5)));
            va0 = __builtin_amdgcn_mfma_f32_32x32x16_bf16(s0, bf, va0, 0, 0, 0);
            va1 = __builtin_amdgcn_mfma_f32_32x32x16_bf16(s1, bf, va1, 0, 0, 0);
        }

        // ---- asum strips: soft = s_lds * normt[p]; k=t>>2, 16 px at strip t&3 ----
        {
            const int rowb = ks << 7;
            const int swz  = (ks & 7) << 4;
            const float* np_ = normt + st4 * 16;
            float a = 0.f;
            #pragma unroll
            for (int g = 0; g < 2; ++g) {
                int off = (st4 << 5) | (g << 4);
                short8 u = *reinterpret_cast<const short8*>(s_lds + (rowb | (off ^ swz)));
                float4 na = *reinterpret_cast<const float4*>(np_ + g * 8);
                float4 nb = *reinterpret_cast<const float4*>(np_ + g * 8 + 4);
                a += b2f((unsigned short)u[0]) * na.x + b2f((unsigned short)u[1]) * na.y +
                     b2f((unsigned short)u[2]) * na.z + b2f((unsigned short)u[3]) * na.w;
                a += b2f((unsigned short)u[4]) * nb.x + b2f((unsigned short)u[5]) * nb.y +
                     b2f((unsigned short)u[6]) * nb.z + b2f((unsigned short)u[7]) * nb.w;
            }
            asum_acc += a;
        }

        // ---- transit write for next half ----
        if (it + 1 < NHALF) {
            __syncthreads();   // C: all xs_lds readers of this half done
            #pragma unroll
            for (int j = 0; j < 8; ++j) {
                int c = c0 + 16 * j;
                uint2 pk;
                pk.x = (unsigned)bfb(v[j].x) | ((unsigned)bfb(v[j].y) << 16);
                pk.y = (unsigned)bfb(v[j].z) | ((unsigned)bfb(v[j].w) << 16);
                *reinterpret_cast<uint2*>(xs_lds + ((c << 7) | ((px4 << 1) ^ tswz))) = pk;
            }
            __syncthreads();   // D: xs(it+1) ready
        }
    }

    // ---- flush partials ----
    if (use_part) {
        unsigned short* pb_ = part + (size_t)blockIdx.x * (K_CL * C_CH) + cB;
        #pragma unroll
        for (int r = 0; r < 16; ++r) {
            const int kr = (r & 3) + 8 * (r >> 2) + 4 * h;
            pb_[(kr)      * C_CH] = bfb(va0[r]);
            pb_[(32 + kr) * C_CH] = bfb(va1[r]);
        }
        float vv = asum_acc;
        vv += __shfl_xor(vv, 1);
        vv += __shfl_xor(vv, 2);
        if (st4 == 0) aspart[blockIdx.x * K_CL + ks] = vv;
    } else {
        float* vb = vlad + (size_t)n * K_CL * C_CH;
        #pragma unroll
        for (int r = 0; r < 16; ++r) {
            const int kr = (r & 3) + 8 * (r >> 2) + 4 * h;
            atomicAdd(vb + (kr)      * C_CH + cB, va0[r]);
            atomicAdd(vb + (32 + kr) * C_CH + cB, va1[r]);
        }
        float vv = asum_acc;
        vv += __shfl_xor(vv, 1);
        vv += __shfl_xor(vv, 2);
        if (st4 == 0) atomicAdd(asum + n * K_CL + ks, vv);
    }
}

// store-path reducer: sum 24 bf16 block partials, subtract asum*centroid, intra-normalize
__global__ void k_rows_part(float* __restrict__ vlad, const unsigned short* __restrict__ part,
                            const float* __restrict__ aspart,
                            const float* __restrict__ cent)
{
    const int bx = blockIdx.x;            // n*64 + k
    const int n = bx >> 6, k = bx & 63;
    const int c = threadIdx.x;            // 128 threads
    const int b0 = n * BPI;
    float v = 0.f, a = 0.f;
    #pragma unroll
    for (int b = 0; b < BPI; ++b) {
        v += b2f(part[(size_t)(b0 + b) * (K_CL * C_CH) + k * C_CH + c]);
        a += aspart[(b0 + b) * K_CL + k];
    }
    v -= a * cent[k * C_CH + c];
    float ssq = v * v;
    #pragma unroll
    for (int m = 32; m >= 1; m >>= 1) ssq += __shfl_xor(ssq, m);
    __shared__ float sb[2];
    if ((threadIdx.x & 63) == 0) sb[threadIdx.x >> 6] = ssq;
    __syncthreads();
    float tot = sb[0] + sb[1];
    float sc = 1.f / fmaxf(sqrtf(tot), EPSF);
    vlad[((size_t)n * K_CL + k) * C_CH + c] = v * sc;
}

// atomic-path reducer (fallback)
__global__ void k_rows(float* __restrict__ vlad, const float* __restrict__ asum,
                       const float* __restrict__ cent)
{
    const int bx = blockIdx.x;            // n*64 + k
    const int n = bx >> 6, k = bx & 63;
    const int c = threadIdx.x;            // 128 threads
    float a = asum[n * K_CL + k];
    size_t idx = ((size_t)n * K_CL + k) * C_CH + c;
    float v = vlad[idx] - a * cent[k * C_CH + c];
    float ssq = v * v;
    #pragma unroll
    for (int m = 32; m >= 1; m >>= 1) ssq += __shfl_xor(ssq, m);
    __shared__ float sb[2];
    if ((threadIdx.x & 63) == 0) sb[threadIdx.x >> 6] = ssq;
    __syncthreads();
    float tot = sb[0] + sb[1];
    float sc = 1.f / fmaxf(sqrtf(tot), EPSF);
    vlad[idx] = v * sc;
}

// projection: pw[j] cached in regs, 4 images per block; final norm fused
__global__ __launch_bounds__(256) void k_proj3(
    const float* __restrict__ vlad, const float* __restrict__ pw,
    const float* __restrict__ pbias, float* __restrict__ out)
{
    const int j  = blockIdx.x;        // 0..127
    const int n0 = blockIdx.y << 2;   // 0,4,...,28
    const int t  = threadIdx.x;
    const float4* wp = (const float4*)(pw + (size_t)j * (K_CL * C_CH));
    float4 wr[8];
    #pragma unroll
    for (int r = 0; r < 8; ++r) wr[r] = wp[t + 256 * r];
    __shared__ float sb[4], sb2[4];
    const float bias = pbias[j];
    #pragma unroll
    for (int u = 0; u < 4; ++u) {
        const int n = n0 + u;
        const float4* vp = (const float4*)(vlad + (size_t)n * (K_CL * C_CH));
        float s = 0.f, nn = 0.f;
        #pragma unroll
        for (int r = 0; r < 8; ++r) {
            float4 a = vp[t + 256 * r];
            s  += a.x * wr[r].x + a.y * wr[r].y + a.z * wr[r].z + a.w * wr[r].w;
            nn += a.x * a.x + a.y * a.y + a.z * a.z + a.w * a.w;
        }
        #pragma unroll
        for (int m = 32; m >= 1; m >>= 1) {
            s  += __shfl_xor(s, m);
            nn += __shfl_xor(nn, m);
        }
        if ((t & 63) == 0) { sb[t >> 6] = s; sb2[t >> 6] = nn; }
        __syncthreads();
        if (t == 0) {
            float tot = sb[0] + sb[1] + sb[2] + sb[3];
            float tss = sb2[0] + sb2[1] + sb2[2] + sb2[3];
            float inv = 1.f / fmaxf(sqrtf(tss), EPSF);
            out[n * C_CH + j] = tot * inv + bias;
        }
        __syncthreads();
    }
}

extern "C" void kernel_launch(void* const* d_in, const int* in_sizes, int n_in,
                              void* d_out, int out_size, void* d_ws, size_t ws_size,
                              hipStream_t stream)
{
    const float* x      = (const float*)d_in[0];
    const float* conv_w = (const float*)d_in[1];
    const float* cent   = (const float*)d_in[2];
    const float* pw     = (const float*)d_in[3];
    const float* pbias  = (const float*)d_in[4];
    float* out = (float*)d_out;
    float* ws  = (float*)d_ws;

    float* vlad            = ws + WS_VLAD;
    float* asum            = ws + WS_ASUM;
    unsigned short* part   = (unsigned short*)(ws + WS_PART);
    float* aspart          = ws + WS_ASP;

    const int use_part = (ws_size >= (size_t)WS_STORE_TOT * sizeof(float)) ? 1 : 0;

    if (!use_part) {
        hipLaunchKernelGGL(k_zero, dim3((WS_ZERO + 255) / 256), dim3(256), 0, stream,
                           ws, WS_ZERO);
    }
    hipLaunchKernelGGL(k_fused9, dim3(N_IMG * BPI), dim3(256), 0, stream,
                       x, conv_w, vlad, asum, part, aspart, use_part);
    if (use_part) {
        hipLaunchKernelGGL(k_rows_part, dim3(N_IMG * K_CL), dim3(C_CH), 0, stream,
                           vlad, part, aspart, cent);
    } else {
        hipLaunchKernelGGL(k_rows, dim3(N_IMG * K_CL), dim3(C_CH), 0, stream,
                           vlad, asum, cent);
    }
    hipLaunchKernelGGL(k_proj3, dim3(C_CH, N_IMG / 4), dim3(256), 0, stream,
                       vlad, pw, pbias, out);
}

// Round 13
// 57.961 us; speedup vs baseline: 1.5823x; 1.5823x over previous
//
#include <hip/hip_runtime.h>
#include <hip/hip_bf16.h>

typedef float f32x16 __attribute__((ext_vector_type(16)));
typedef short short8 __attribute__((ext_vector_type(8)));

#define N_IMG 32
#define C_CH  128
#define HW    9216
#define K_CL  64
#define EPSF  1e-12f

#define BPI   16      // blocks per image (grid 512 = exactly 2/CU)
#define PPB   576     // pixels per block
#define NHALF 9       // 9 half-tiles of 64 pixels

// ws layout (floats)
#define WS_VLAD 0
#define WS_ASUM (N_IMG*K_CL*C_CH)              // 262144
#define WS_ZERO (WS_ASUM + N_IMG*K_CL)         // 264192 (zeroed prefix, atomic path)
#define WS_PART WS_ZERO
#define NPART   (N_IMG*BPI)                    // 512
// part stored as bf16 (ushort): NPART*K_CL*C_CH shorts -> /2 floats
#define WS_ASP  (WS_PART + NPART*K_CL*C_CH/2)  // + 2097152
#define WS_STORE_TOT (WS_ASP + NPART*K_CL)     // ~2.36M floats (< prior 3.46M need)

__device__ __forceinline__ unsigned short bfb(float f) {
    __hip_bfloat16 h = __float2bfloat16(f);   // RNE
    return *reinterpret_cast<unsigned short*>(&h);
}
__device__ __forceinline__ float b2f(unsigned short s) {
    return __uint_as_float(((unsigned)s) << 16);
}

typedef const __attribute__((address_space(1))) void gv_t;
typedef __attribute__((address_space(3))) void lv_t;
__device__ __forceinline__ void gload16(const void* g, void* l) {
    __builtin_amdgcn_global_load_lds((gv_t*)g, (lv_t*)l, 16, 0, 0);
}
#define SBAR()  __builtin_amdgcn_s_barrier()
#define WAITL() do { asm volatile("s_waitcnt lgkmcnt(0)" ::: "memory"); \
                     __builtin_amdgcn_sched_barrier(0); } while (0)
#define WAITV() do { asm volatile("s_waitcnt vmcnt(0)" ::: "memory"); \
                     __builtin_amdgcn_sched_barrier(0); } while (0)

__global__ void k_zero(float* __restrict__ p, int cnt) {
    int i = blockIdx.x * blockDim.x + threadIdx.x;
    if (i < cnt) p[i] = 0.f;
}

__global__ __launch_bounds__(256, 2) void k_fused10(
    const float* __restrict__ x, const float* __restrict__ conv_w,
    float* __restrict__ vlad, float* __restrict__ asum,
    unsigned short* __restrict__ part, float* __restrict__ aspart, int use_part)
{
    // cw: pitch 256B swz ^((k&7)<<4). s/x: pitch 128B swz ^((row&7)<<4). xs: linear.
    __shared__ __align__(16) char cw_lds[64 * 256];    // conv_w bf16 [64k][128c] 16KB
    __shared__ __align__(16) char xs_lds[128 * 256];   // raw x fp32 [128c][64p]  32KB
    __shared__ __align__(16) char s_lds [64 * 128];    // e raw bf16 [64k][64p]    8KB
    __shared__ __align__(16) char x_lds [128 * 128];   // x*scn*inv bf16 [128c][64p] 16KB
    __shared__ __align__(16) float smpart[2][64];
    __shared__ __align__(16) float invt[64];

    const int t  = threadIdx.x;
    const int w  = t >> 6;          // wave 0..3
    const int l  = t & 63;
    const int lp = l & 31;
    const int h  = l >> 5;
    const int n    = blockIdx.x / BPI;
    const int pblk = (blockIdx.x % BPI) * PPB;

    // ---- stage conv_w -> bf16, swizzled ----
    #pragma unroll
    for (int r = 0; r < 16; ++r) {
        int e  = t + 256 * r;
        int k  = e >> 6;
        int c2 = (e & 63) << 1;
        unsigned pa = (unsigned)bfb(conv_w[k * C_CH + c2]) |
                      ((unsigned)bfb(conv_w[k * C_CH + c2 + 1]) << 16);
        int addr = (((k << 8) | (c2 << 1)) ^ ((k & 7) << 4));
        *reinterpret_cast<unsigned*>(cw_lds + addr) = pa;
    }

    f32x16 va0, va1;
    #pragma unroll
    for (int r = 0; r < 16; ++r) { va0[r] = 0.f; va1[r] = 0.f; }
    float asum_acc = 0.f;

    const int kh  = w >> 1;                 // logits k-half
    const int p   = ((w & 1) << 5) + lp;    // pixel 0..63
    const int p2  = p << 1;
    const int ks  = t >> 2;                 // asum k row
    const int st4 = t & 3;                  // asum strip (16 px)
    const float* xbase = x + (size_t)n * C_CH * HW;

    // DMA assignment: lane covers (c_local = l>>4, 4 px = (l&15)*4)
    const int pxo   = (l & 15) << 2;
    const int crow0 = (w << 5) + (l >> 4);

    // LDS bases
    const int swzL = (lp & 7) << 4;
    const int hx   = h << 4;
    const int bCW  = (((kh << 5) + lp) << 8) | (hx ^ swzL);   // logits A (^ s<<5)
    const int bXS  = (p << 2) + (h << 11);                     // xs col read (+ c<<8)
    const int cB   = (w << 5) + lp;                            // VLAD c-column
    const int bXf  = (cB << 7) | (hx ^ swzL);                  // x_lds read (cB&7==lp&7)
    const int bS0  = (lp << 7)        | (hx ^ swzL);           // s_lds rows lp
    const int bS1  = ((32 + lp) << 7) | (hx ^ swzL);           // s_lds rows 32+lp
    int baseS[4];                                              // e-store bases
    #pragma unroll
    for (int j = 0; j < 4; ++j)
        baseS[j] = (kh << 12) + (h << 9) + (p2 ^ (j << 4) ^ (h << 6));

    // ---- prologue: issue DMA for half 0, wait everything, barrier ----
    {
        const float* src0 = xbase + pblk + pxo;
        #pragma unroll
        for (int j = 0; j < 8; ++j)
            gload16(src0 + (size_t)(crow0 + 4 * j) * HW,
                    xs_lds + (((w << 5) + 4 * j) << 8));
    }
    WAITL(); WAITV(); SBAR();

    for (int it = 0; it < NHALF; ++it) {
        if (it > 0) { WAITV(); SBAR(); }   // F: xs[it] landed everywhere

        // ---- frag assembly + sumsq from xs fp32 (conflict-free column reads) ----
        float ss = 0.f;
        short8 xb[8];
        #pragma unroll
        for (int s8 = 0; s8 < 8; ++s8) {
            #pragma unroll
            for (int i = 0; i < 8; ++i) {
                float f = *reinterpret_cast<const float*>(
                    xs_lds + bXS + ((16 * s8 + i) << 8));
                ss += f * f;
                xb[s8][i] = (short)bfb(f);
            }
        }
        ss += __shfl_xor(ss, 32);
        const float scn = 1.f / fmaxf(sqrtf(ss), EPSF);

        WAITL(); SBAR();                   // E: all waves done reading xs[it]

        // ---- issue DMA for half it+1 (in flight across the whole iteration) ----
        if (it + 1 < NHALF) {
            const float* src0 = xbase + pblk + (it + 1) * 64 + pxo;
            #pragma unroll
            for (int j = 0; j < 8; ++j)
                gload16(src0 + (size_t)(crow0 + 4 * j) * HW,
                        xs_lds + (((w << 5) + 4 * j) << 8));
        }

        // ---- logits MFMA: [32k(kh) x 32p], K=128 ----
        f32x16 d;
        #pragma unroll
        for (int r = 0; r < 16; ++r) d[r] = 0.f;
        #pragma unroll
        for (int s8 = 0; s8 < 8; ++s8) {
            short8 a = *reinterpret_cast<const short8*>(cw_lds + (bCW ^ (s8 << 5)));
            d = __builtin_amdgcn_mfma_f32_32x32x16_bf16(a, xb[s8], d, 0, 0, 0);
        }

        // ---- e = exp(d*scn) (bounded, no max needed); cross-wave denom ----
        float e[16];
        float sm = 0.f;
        #pragma unroll
        for (int r = 0; r < 16; ++r) { e[r] = __expf(d[r] * scn); sm += e[r]; }
        sm += __shfl_xor(sm, 32);
        if (h == 0) smpart[kh][p] = sm;
        WAITL(); SBAR();                   // A: smpart visible; prev readers done

        const float inv = 1.f / (smpart[0][p] + smpart[1][p]);
        const float sc2 = scn * inv;

        // ---- e-stores (raw e) to s_lds [64k][64p] ----
        #pragma unroll
        for (int r = 0; r < 16; ++r) {
            const int imm = ((r & 3) << 7) + ((r >> 2) << 10);
            *reinterpret_cast<short*>(s_lds + (baseS[r & 3] + imm)) = (short)bfb(e[r]);
        }
        // ---- x-stores (waves 0,1 cover all (c,p)); invt ----
        if (kh == 0) {
            #pragma unroll
            for (int j = 0; j < 8; ++j) {
                const int bx_ = (p2 ^ (j << 4)) + (h << 10);
                #pragma unroll
                for (int s = 0; s < 8; ++s)
                    *reinterpret_cast<short*>(x_lds + (bx_ + ((16 * s + j) << 7))) =
                        (short)bfb(b2f((unsigned short)xb[s][j]) * sc2);
            }
            if (h == 0) invt[p] = inv;
        }
        WAITL(); SBAR();                   // B: s/x/invt ready

        // ---- VLAD MFMA: [64k x 128c], K=64 ----
        #pragma unroll
        for (int sp = 0; sp < 4; ++sp) {
            short8 bf = *reinterpret_cast<const short8*>(x_lds + (bXf ^ (sp << 5)));
            short8 s0 = *reinterpret_cast<const short8*>(s_lds + (bS0 ^ (sp << 5)));
            short8 s1 = *reinterpret_cast<const short8*>(s_lds + (bS1 ^ (sp << 5)));
            va0 = __builtin_amdgcn_mfma_f32_32x32x16_bf16(s0, bf, va0, 0, 0, 0);
            va1 = __builtin_amdgcn_mfma_f32_32x32x16_bf16(s1, bf, va1, 0, 0, 0);
        }

        // ---- asum strips: soft = e * invt[p]; k=ks, 16 px at strip st4 ----
        {
            const int rowb = ks << 7;
            const int swz  = (ks & 7) << 4;
            const float* ivp = invt + (st4 << 4);
            float a = 0.f;
            #pragma unroll
            for (int g = 0; g < 2; ++g) {
                int off = (st4 << 5) | (g << 4);
                short8 u = *reinterpret_cast<const short8*>(s_lds + (rowb | (off ^ swz)));
                float4 ia = *reinterpret_cast<const float4*>(ivp + g * 8);
                float4 ib = *reinterpret_cast<const float4*>(ivp + g * 8 + 4);
                a += b2f((unsigned short)u[0]) * ia.x + b2f((unsigned short)u[1]) * ia.y +
                     b2f((unsigned short)u[2]) * ia.z + b2f((unsigned short)u[3]) * ia.w;
                a += b2f((unsigned short)u[4]) * ib.x + b2f((unsigned short)u[5]) * ib.y +
                     b2f((unsigned short)u[6]) * ib.z + b2f((unsigned short)u[7]) * ib.w;
            }
            asum_acc += a;
        }
    }

    // ---- flush partials ----
    if (use_part) {
        unsigned short* pb_ = part + (size_t)blockIdx.x * (K_CL * C_CH) + cB;
        #pragma unroll
        for (int r = 0; r < 16; ++r) {
            const int kr = (r & 3) + 8 * (r >> 2) + 4 * h;
            pb_[(kr)      * C_CH] = bfb(va0[r]);
            pb_[(32 + kr) * C_CH] = bfb(va1[r]);
        }
        float vv = asum_acc;
        vv += __shfl_xor(vv, 1);
        vv += __shfl_xor(vv, 2);
        if (st4 == 0) aspart[blockIdx.x * K_CL + ks] = vv;
    } else {
        float* vb = vlad + (size_t)n * K_CL * C_CH;
        #pragma unroll
        for (int r = 0; r < 16; ++r) {
            const int kr = (r & 3) + 8 * (r >> 2) + 4 * h;
            atomicAdd(vb + (kr)      * C_CH + cB, va0[r]);
            atomicAdd(vb + (32 + kr) * C_CH + cB, va1[r]);
        }
        float vv = asum_acc;
        vv += __shfl_xor(vv, 1);
        vv += __shfl_xor(vv, 2);
        if (st4 == 0) atomicAdd(asum + n * K_CL + ks, vv);
    }
}

// store-path reducer: sum 16 bf16 block partials, subtract asum*centroid, intra-normalize
__global__ void k_rows_part(float* __restrict__ vlad, const unsigned short* __restrict__ part,
                            const float* __restrict__ aspart,
                            const float* __restrict__ cent)
{
    const int bx = blockIdx.x;            // n*64 + k
    const int n = bx >> 6, k = bx & 63;
    const int c = threadIdx.x;            // 128 threads
    const int b0 = n * BPI;
    float v = 0.f, a = 0.f;
    #pragma unroll
    for (int b = 0; b < BPI; ++b) {
        v += b2f(part[(size_t)(b0 + b) * (K_CL * C_CH) + k * C_CH + c]);
        a += aspart[(b0 + b) * K_CL + k];
    }
    v -= a * cent[k * C_CH + c];
    float ssq = v * v;
    #pragma unroll
    for (int m = 32; m >= 1; m >>= 1) ssq += __shfl_xor(ssq, m);
    __shared__ float sb[2];
    if ((threadIdx.x & 63) == 0) sb[threadIdx.x >> 6] = ssq;
    __syncthreads();
    float tot = sb[0] + sb[1];
    float sc = 1.f / fmaxf(sqrtf(tot), EPSF);
    vlad[((size_t)n * K_CL + k) * C_CH + c] = v * sc;
}

// atomic-path reducer (fallback)
__global__ void k_rows(float* __restrict__ vlad, const float* __restrict__ asum,
                       const float* __restrict__ cent)
{
    const int bx = blockIdx.x;
    const int n = bx >> 6, k = bx & 63;
    const int c = threadIdx.x;
    float a = asum[n * K_CL + k];
    size_t idx = ((size_t)n * K_CL + k) * C_CH + c;
    float v = vlad[idx] - a * cent[k * C_CH + c];
    float ssq = v * v;
    #pragma unroll
    for (int m = 32; m >= 1; m >>= 1) ssq += __shfl_xor(ssq, m);
    __shared__ float sb[2];
    if ((threadIdx.x & 63) == 0) sb[threadIdx.x >> 6] = ssq;
    __syncthreads();
    float tot = sb[0] + sb[1];
    float sc = 1.f / fmaxf(sqrtf(tot), EPSF);
    vlad[idx] = v * sc;
}

// projection: pw[j] cached in regs, 4 images per block; final norm fused
__global__ __launch_bounds__(256) void k_proj3(
    const float* __restrict__ vlad, const float* __restrict__ pw,
    const float* __restrict__ pbias, float* __restrict__ out)
{
    const int j  = blockIdx.x;
    const int n0 = blockIdx.y << 2;
    const int t  = threadIdx.x;
    const float4* wp = (const float4*)(pw + (size_t)j * (K_CL * C_CH));
    float4 wr[8];
    #pragma unroll
    for (int r = 0; r < 8; ++r) wr[r] = wp[t + 256 * r];
    __shared__ float sb[4], sb2[4];
    const float bias = pbias[j];
    #pragma unroll
    for (int u = 0; u < 4; ++u) {
        const int n = n0 + u;
        const float4* vp = (const float4*)(vlad + (size_t)n * (K_CL * C_CH));
        float s = 0.f, nn = 0.f;
        #pragma unroll
        for (int r = 0; r < 8; ++r) {
            float4 a = vp[t + 256 * r];
            s  += a.x * wr[r].x + a.y * wr[r].y + a.z * wr[r].z + a.w * wr[r].w;
            nn += a.x * a.x + a.y * a.y + a.z * a.z + a.w * a.w;
        }
        #pragma unroll
        for (int m = 32; m >= 1; m >>= 1) {
            s  += __shfl_xor(s, m);
            nn += __shfl_xor(nn, m);
        }
        if ((t & 63) == 0) { sb[t >> 6] = s; sb2[t >> 6] = nn; }
        __syncthreads();
        if (t == 0) {
            float tot = sb[0] + sb[1] + sb[2] + sb[3];
            float tss = sb2[0] + sb2[1] + sb2[2] + sb2[3];
            float inv = 1.f / fmaxf(sqrtf(tss), EPSF);
            out[n * C_CH + j] = tot * inv + bias;
        }
        __syncthreads();
    }
}

extern "C" void kernel_launch(void* const* d_in, const int* in_sizes, int n_in,
                              void* d_out, int out_size, void* d_ws, size_t ws_size,
                              hipStream_t stream)
{
    const float* x      = (const float*)d_in[0];
    const float* conv_w = (const float*)d_in[1];
    const float* cent   = (const float*)d_in[2];
    const float* pw     = (const float*)d_in[3];
    const float* pbias  = (const float*)d_in[4];
    float* out = (float*)d_out;
    float* ws  = (float*)d_ws;

    float* vlad            = ws + WS_VLAD;
    float* asum            = ws + WS_ASUM;
    unsigned short* part   = (unsigned short*)(ws + WS_PART);
    float* aspart          = ws + WS_ASP;

    const int use_part = (ws_size >= (size_t)WS_STORE_TOT * sizeof(float)) ? 1 : 0;

    if (!use_part) {
        hipLaunchKernelGGL(k_zero, dim3((WS_ZERO + 255) / 256), dim3(256), 0, stream,
                           ws, WS_ZERO);
    }
    hipLaunchKernelGGL(k_fused10, dim3(N_IMG * BPI), dim3(256), 0, stream,
                       x, conv_w, vlad, asum, part, aspart, use_part);
    if (use_part) {
        hipLaunchKernelGGL(k_rows_part, dim3(N_IMG * K_CL), dim3(C_CH), 0, stream,
                           vlad, part, aspart, cent);
    } else {
        hipLaunchKernelGGL(k_rows, dim3(N_IMG * K_CL), dim3(C_CH), 0, stream,
                           vlad, asum, cent);
    }
    hipLaunchKernelGGL(k_proj3, dim3(C_CH, N_IMG / 4), dim3(256), 0, stream,
                       vlad, pw, pbias, out);
}